// Round 4
// baseline (265.706 us; speedup 1.0000x reference)
//
#include <hip/hip_runtime.h>

// R29 — resubmit of R28 (container failed; NT-store theory still untested).
// __builtin_nontemporal_store via native ext_vector_type(4) float — emits
// global_store_dwordx4 with nt. Numerics identical to census-proven R25:
//   acc += x; spike = acc >= thr; acc = spike?0:acc;
//   thr = fmaf(thr, 0.9f, 0.1f*|x|)   <- single rounding (matches XLA fusion)
// Theory under test: 268 MB write-once output > 256 MB L3; normal stores
// stream dead data through L2/L3 (allocate + dirty-evict), capping write BW
// at ~1.0 TB/s. nt stores bypass cache retention -> target 6.3 TB/s ceiling.

#define TSTEPS 32
#define BDIM 32
#define FDIM 65536

typedef float floatx4 __attribute__((ext_vector_type(4)));

__global__ __launch_bounds__(256) void spike_fma_f32_nt_kernel(
    const float* __restrict__ x, float* __restrict__ out) {
    int gid = blockIdx.x * blockDim.x + threadIdx.x;   // 0 .. B*F/4-1
    int fi  = gid & (FDIM / 4 - 1);                    // 0..16383
    int b   = gid >> 14;                               // F/4 = 16384
    int f   = fi << 2;

    const floatx4 xv = *reinterpret_cast<const floatx4*>(x + (size_t)b * FDIM + f);
    float xs[4] = {xv.x, xv.y, xv.z, xv.w};

    float acc[4], thr[4], ad[4];
#pragma unroll
    for (int i = 0; i < 4; ++i) {
        acc[i] = 0.0f;
        thr[i] = 0.5f;
        ad[i]  = 0.1f * fabsf(xs[i]);   // one rounding
    }

    float* outb = out + (size_t)b * TSTEPS * FDIM + f;

#pragma unroll
    for (int t = 0; t < TSTEPS; ++t) {
        floatx4 sp;
#pragma unroll
        for (int e = 0; e < 4; ++e) {
            acc[e] = acc[e] + xs[e];
            bool m = acc[e] >= thr[e];
            sp[e]  = m ? 1.0f : 0.0f;
            acc[e] = m ? 0.0f : acc[e];
            thr[e] = __builtin_fmaf(thr[e], 0.9f, ad[e]);   // fused, 1 rounding
        }
        __builtin_nontemporal_store(
            sp, reinterpret_cast<floatx4*>(outb + (size_t)t * FDIM));
    }
}

extern "C" void kernel_launch(void* const* d_in, const int* in_sizes, int n_in,
                              void* d_out, int out_size, void* d_ws, size_t ws_size,
                              hipStream_t stream) {
    (void)in_sizes; (void)n_in; (void)d_ws; (void)ws_size; (void)out_size;
    const float* x = (const float*)d_in[0];
    float* out     = (float*)d_out;
    const int total_threads = BDIM * FDIM / 4;   // 524288
    spike_fma_f32_nt_kernel<<<total_threads / 256, 256, 0, stream>>>(x, out);
}